// Round 4
// baseline (24.061 us; speedup 1.0000x reference)
//
#include <hip/hip_runtime.h>

// MultiLabelEmbedding: mean-pooled embedding bag.
// ROUND 4 = DISCRIMINATOR EXPERIMENT, kernel byte-identical to round 3.
// Rounds 2 & 3 (structurally different kernels) both timed 14.67 us within
// 0.02% -> shared floor. Launch the same kernel TWICE in the captured graph:
//   - if dur ~= 29 us  -> kernel-bound at ~14.7 us (gather-BW ceiling is real)
//   - if dur ~= 16-19  -> ~12 us is fixed replay overhead; kernel is ~2-4 us
// Second launch is idempotent (recomputes and overwrites identical output).

#define BAGS      16384
#define BAG_LEN   50
#define EMB_DIM   32

__global__ __launch_bounds__(256) void multilabel_embed_kernel(
    const float* __restrict__ table,
    const int*   __restrict__ indices,
    const int*   __restrict__ lengths,
    float*       __restrict__ out)
{
    const int wavesPerBlock = blockDim.x >> 6;                    // 4
    int bag = blockIdx.x * wavesPerBlock + (threadIdx.x >> 6);
    bag = __builtin_amdgcn_readfirstlane(bag);                    // wave-uniform
    if (bag >= BAGS) return;

    const int lane = threadIdx.x & 63;
    const int sub  = (lane & 7) << 2;   // float offset within the 32-float row
    const int eg   = lane >> 3;         // element group 0..7

    int len = lengths[bag];
    len = __builtin_amdgcn_readfirstlane(len);                    // scalar
    if (len < 0) len = 0;
    if (len > BAG_LEN) len = BAG_LEN;

    const int* __restrict__ idx = indices + bag * BAG_LEN;

    float4 acc = make_float4(0.f, 0.f, 0.f, 0.f);
    for (int base = 0; base < len; base += 16) {
        const int l0 = base + eg;
        const int l1 = base + 8 + eg;
        const int i0 = idx[(l0 < len) ? l0 : 0];
        const int i1 = idx[(l1 < len) ? l1 : 0];
        const float4 r0 = *reinterpret_cast<const float4*>(
            table + (size_t)i0 * EMB_DIM + sub);
        const float4 r1 = *reinterpret_cast<const float4*>(
            table + (size_t)i1 * EMB_DIM + sub);
        const bool v0 = (l0 < len), v1 = (l1 < len);
        acc.x += v0 ? r0.x : 0.f;  acc.y += v0 ? r0.y : 0.f;
        acc.z += v0 ? r0.z : 0.f;  acc.w += v0 ? r0.w : 0.f;
        acc.x += v1 ? r1.x : 0.f;  acc.y += v1 ? r1.y : 0.f;
        acc.z += v1 ? r1.z : 0.f;  acc.w += v1 ? r1.w : 0.f;
    }

#pragma unroll
    for (int m = 8; m < 64; m <<= 1) {
        acc.x += __shfl_xor(acc.x, m);
        acc.y += __shfl_xor(acc.y, m);
        acc.z += __shfl_xor(acc.z, m);
        acc.w += __shfl_xor(acc.w, m);
    }

    if (eg == 0) {   // lanes 0..7 write the 128B output row
        const float inv = 1.0f / (float)(len > 0 ? len : 1);
        acc.x *= inv; acc.y *= inv; acc.z *= inv; acc.w *= inv;
        *reinterpret_cast<float4*>(out + (size_t)bag * EMB_DIM + sub) = acc;
    }
}

extern "C" void kernel_launch(void* const* d_in, const int* in_sizes, int n_in,
                              void* d_out, int out_size, void* d_ws, size_t ws_size,
                              hipStream_t stream) {
    const float* table   = (const float*)d_in[0];
    const int*   indices = (const int*)d_in[1];
    const int*   lengths = (const int*)d_in[2];
    float*       out     = (float*)d_out;

    const int threads = 256;                       // 4 waves = 4 bags per block
    const int grid = BAGS / 4;                     // 4096 blocks, 16384 waves

    // Launch TWICE (idempotent): discriminates kernel-bound vs overhead-floor.
    multilabel_embed_kernel<<<grid, threads, 0, stream>>>(table, indices, lengths, out);
    multilabel_embed_kernel<<<grid, threads, 0, stream>>>(table, indices, lengths, out);
}

// Round 5
// 13.481 us; speedup vs baseline: 1.7848x; 1.7848x over previous
//
#include <hip/hip_runtime.h>

// MultiLabelEmbedding: mean-pooled embedding bag.
//  embed_table: float32 [100000, 32]   d_in[0]
//  indices:     int32   [16384, 50]    d_in[1]
//  lengths:     int32   [16384]        d_in[2]
//  out:         float32 [16384, 32]
//
// Round 5: kill the dependent idx->gather chain.
//  Round 4 discriminator: kernel ~9.4 us marginal + ~5.3 us replay overhead.
//  Round 3 loop serialized on per-iteration idx loads (memory -> address ->
//  gather -> next idx). Now: ONE coalesced load grabs all 50 indices into
//  lane registers; per-element index comes from __shfl (ds_bpermute,
//  in-register); all 7 gather dwordx4 issue back-to-back (full unroll,
//  clamp-predicated), then one accumulate pass.
//  Per-wave serial chain: idx_load + shfl + ONE gather latency.
//  Clamped (l>=len) groups re-read the bag's idx[0] row -> same cache line,
//  coalesced; predicated out of the accumulate.

#define BAGS      16384
#define BAG_LEN   50
#define EMB_DIM   32
#define NSTEP     7        // ceil(50/8) element-groups of 8

__global__ __launch_bounds__(256) void multilabel_embed_kernel(
    const float* __restrict__ table,
    const int*   __restrict__ indices,
    const int*   __restrict__ lengths,
    float*       __restrict__ out)
{
    const int wavesPerBlock = blockDim.x >> 6;                    // 4
    int bag = blockIdx.x * wavesPerBlock + (threadIdx.x >> 6);
    bag = __builtin_amdgcn_readfirstlane(bag);                    // wave-uniform
    if (bag >= BAGS) return;

    const int lane = threadIdx.x & 63;
    const int sub  = (lane & 7) << 2;   // float offset within the 32-float row
    const int eg   = lane >> 3;         // element group 0..7

    int len = lengths[bag];
    len = __builtin_amdgcn_readfirstlane(len);                    // scalar
    if (len < 0) len = 0;
    if (len > BAG_LEN) len = BAG_LEN;

    // ONE coalesced load: all 50 bag indices into lane registers
    const int* __restrict__ idx = indices + bag * BAG_LEN;
    const int myidx = idx[(lane < BAG_LEN) ? lane : (BAG_LEN - 1)];

    // Phase 1: resolve per-step indices in-register (no memory loads)
    int  ix[NSTEP];
    bool valid[NSTEP];
#pragma unroll
    for (int s = 0; s < NSTEP; ++s) {
        const int l = s * 8 + eg;
        valid[s] = (l < len);
        const int cl = valid[s] ? l : 0;
        ix[s] = __shfl(myidx, cl);          // ds_bpermute, ~50cy, pipelined
    }

    // Phase 2: issue ALL gathers back-to-back (7 independent dwordx4)
    float4 r[NSTEP];
#pragma unroll
    for (int s = 0; s < NSTEP; ++s) {
        r[s] = *reinterpret_cast<const float4*>(
            table + (size_t)ix[s] * EMB_DIM + sub);
    }

    // Phase 3: predicated accumulate
    float4 acc = make_float4(0.f, 0.f, 0.f, 0.f);
#pragma unroll
    for (int s = 0; s < NSTEP; ++s) {
        acc.x += valid[s] ? r[s].x : 0.f;
        acc.y += valid[s] ? r[s].y : 0.f;
        acc.z += valid[s] ? r[s].z : 0.f;
        acc.w += valid[s] ? r[s].w : 0.f;
    }

    // reduce over element groups: lanes l, l^8, l^16, l^32 share `sub`
#pragma unroll
    for (int m = 8; m < 64; m <<= 1) {
        acc.x += __shfl_xor(acc.x, m);
        acc.y += __shfl_xor(acc.y, m);
        acc.z += __shfl_xor(acc.z, m);
        acc.w += __shfl_xor(acc.w, m);
    }

    if (eg == 0) {   // lanes 0..7 write the 128B output row
        const float inv = 1.0f / (float)(len > 0 ? len : 1);
        acc.x *= inv; acc.y *= inv; acc.z *= inv; acc.w *= inv;
        *reinterpret_cast<float4*>(out + (size_t)bag * EMB_DIM + sub) = acc;
    }
}

extern "C" void kernel_launch(void* const* d_in, const int* in_sizes, int n_in,
                              void* d_out, int out_size, void* d_ws, size_t ws_size,
                              hipStream_t stream) {
    const float* table   = (const float*)d_in[0];
    const int*   indices = (const int*)d_in[1];
    const int*   lengths = (const int*)d_in[2];
    float*       out     = (float*)d_out;

    const int threads = 256;                       // 4 waves = 4 bags per block
    const int grid = BAGS / 4;                     // 4096 blocks, 16384 waves

    multilabel_embed_kernel<<<grid, threads, 0, stream>>>(table, indices, lengths, out);
}